// Round 1
// baseline (8912.560 us; speedup 1.0000x reference)
//
#include <hip/hip_runtime.h>

#define NB 4096
#define NSEQ 64
#define CDIM 96
#define NH 3
#define HDM 32
#define LSTR 36  // LDS row stride in floats: 144B, 16B-aligned for b128

// ---------------- bias precompute: bias[type][h][n][m] = tbl_type[rel[n,m], h]
__global__ __launch_bounds__(256) void bias_pre_kernel(
    const float* __restrict__ tcv, const float* __restrict__ tsv,
    const float* __restrict__ tch, const float* __restrict__ tsh,
    const int* __restrict__ rel, float* __restrict__ bias) {
  int idx = blockIdx.x * 256 + threadIdx.x;
  if (idx >= 4 * NH * NSEQ * NSEQ) return;
  int t = idx / (NH * NSEQ * NSEQ);
  int r = idx - t * (NH * NSEQ * NSEQ);
  int h = r / (NSEQ * NSEQ);
  int nm = r - h * (NSEQ * NSEQ);
  const float* tbl = (t == 0) ? tcv : (t == 1) ? tsv : (t == 2) ? tch : tsh;
  bias[idx] = tbl[rel[nm] * NH + h];
}

// ---------------- main fused kernel: one block per window
// wave 0: type cv  (q=qsv from S, K=ks(S), V=vs(S))   scale
// wave 1: type sv  (q=qev from E, K=ke(E), V=ve(E))   1
// wave 2: type ch  (q=qeh from E, K=ke(E), V=ve(E))   scale
// wave 3: type sh  (q=qsh from S, K=ks(S), V=vs(S))   scale^2
// shared slices: w0->ks(buf0) w1->ke(buf1) w2->ve(buf2) w3->vs(buf3)
__global__ __launch_bounds__(256, 1) void rwa_kernel(
    const float* __restrict__ Xin, const float* __restrict__ Xst,
    const float* __restrict__ Ws, const float* __restrict__ bs,
    const float* __restrict__ We, const float* __restrict__ be,
    const float* __restrict__ Wpv, const float* __restrict__ bpv,
    const float* __restrict__ Wph, const float* __restrict__ bph,
    const float* __restrict__ bias, float* __restrict__ out) {
  const int b = blockIdx.x;
  const int t = threadIdx.x;
  const int w_ = t >> 6;
  const int lane = t & 63;  // query row n
  const int wu = __builtin_amdgcn_readfirstlane(w_);

  __shared__ float buf[4][NSEQ][LSTR];

  const float SC = 0.17677669529663687f;  // 32^-0.5

  const float* X  = (wu == 0 || wu == 3) ? Xst : Xin;
  const float* Wt = (wu == 0 || wu == 3) ? Ws : We;
  const float* bt = (wu == 0 || wu == 3) ? bs : be;
  const int qf = (wu < 2) ? 2 : 3;                 // qsv/qev : qeh/qsh
  const int sf = (wu < 2) ? 0 : 1;                 // k-slice : v-slice
  const int kb = (wu == 1 || wu == 2) ? 1 : 0;     // K buffer
  const int vb = (wu == 1 || wu == 2) ? 2 : 3;     // V buffer
  const float sc = (wu == 0 || wu == 2) ? SC : ((wu == 1) ? 1.0f : SC * SC);

  const int n2 = t >> 2;   // row for output projection
  const int qq = t & 3;    // channel quarter (24 channels each)

  float outAcc[24], stAcc[24];
#pragma unroll
  for (int j = 0; j < 24; j++) {
    outAcc[j] = bpv[qq * 24 + j];
    stAcc[j]  = bph[qq * 24 + j];
  }

  const float* Xbase = X + ((size_t)b * NSEQ + lane) * CDIM;

#pragma unroll 1
  for (int h = 0; h < NH; h++) {
    // ---------- phase 1: projections (q into regs, shared slice into LDS)
    const float* Xp = Xbase;
    asm volatile("" : "+v"(Xp));  // defeat LICM: reload X row each head
    float Xr[CDIM];
#pragma unroll
    for (int k4 = 0; k4 < CDIM / 4; k4++) {
      float4 v = ((const float4*)Xp)[k4];
      Xr[4 * k4 + 0] = v.x; Xr[4 * k4 + 1] = v.y;
      Xr[4 * k4 + 2] = v.z; Xr[4 * k4 + 3] = v.w;
    }

    float qv[HDM];
#pragma unroll
    for (int d0 = 0; d0 < HDM; d0 += 4) {
      const int ch = qf * CDIM + h * HDM + d0;
      const float* wr = Wt + (size_t)ch * CDIM;
      float a0 = bt[ch + 0], a1 = bt[ch + 1], a2 = bt[ch + 2], a3 = bt[ch + 3];
#pragma unroll
      for (int k = 0; k < CDIM; k++) {
        float x = Xr[k];
        a0 += x * wr[k];
        a1 += x * wr[CDIM + k];
        a2 += x * wr[2 * CDIM + k];
        a3 += x * wr[3 * CDIM + k];
      }
      qv[d0] = a0; qv[d0 + 1] = a1; qv[d0 + 2] = a2; qv[d0 + 3] = a3;
    }
#pragma unroll
    for (int d0 = 0; d0 < HDM; d0 += 4) {
      const int ch = sf * CDIM + h * HDM + d0;
      const float* wr = Wt + (size_t)ch * CDIM;
      float a0 = bt[ch + 0], a1 = bt[ch + 1], a2 = bt[ch + 2], a3 = bt[ch + 3];
#pragma unroll
      for (int k = 0; k < CDIM; k++) {
        float x = Xr[k];
        a0 += x * wr[k];
        a1 += x * wr[CDIM + k];
        a2 += x * wr[2 * CDIM + k];
        a3 += x * wr[3 * CDIM + k];
      }
      buf[wu][lane][d0] = a0; buf[wu][lane][d0 + 1] = a1;
      buf[wu][lane][d0 + 2] = a2; buf[wu][lane][d0 + 3] = a3;
    }
    __syncthreads();

    // ---------- phase 2: attention (whole row per lane)
    float l[NSEQ];
    const float* brow = bias + (((size_t)wu * NH + h) * NSEQ + lane) * NSEQ;
#pragma unroll
    for (int m = 0; m < NSEQ; m++) {
      float a = 0.f;
#pragma unroll
      for (int d = 0; d < HDM; d++) a += qv[d] * buf[kb][m][d];
      l[m] = sc * a + brow[m];
    }
    float mx = -1e30f;
#pragma unroll
    for (int m = 0; m < NSEQ; m++) mx = fmaxf(mx, l[m]);
    float ssum = 0.f;
#pragma unroll
    for (int m = 0; m < NSEQ; m++) { l[m] = __expf(l[m] - mx); ssum += l[m]; }
    float inv = 1.0f / ssum;

    float acc[HDM];
#pragma unroll
    for (int d = 0; d < HDM; d++) acc[d] = 0.f;
#pragma unroll
    for (int m = 0; m < NSEQ; m++) {
      float p = l[m];
#pragma unroll
      for (int d = 0; d < HDM; d++) acc[d] += p * buf[vb][m][d];
    }
    __syncthreads();  // all waves done reading K/V before overwrite
#pragma unroll
    for (int d = 0; d < HDM; d++) buf[wu][lane][d] = acc[d] * inv;
    __syncthreads();

    // ---------- phase 3: accumulate output projections
    // buf0=A_cv buf1=A_sv buf2=A_ch buf3=A_sh
    float a0r[HDM], a1r[HDM], a2r[HDM], a3r[HDM];
#pragma unroll
    for (int d = 0; d < HDM; d++) {
      a0r[d] = buf[0][n2][d]; a1r[d] = buf[1][n2][d];
      a2r[d] = buf[2][n2][d]; a3r[d] = buf[3][n2][d];
    }
#pragma unroll
    for (int j = 0; j < 24; j++) {
      const int c = qq * 24 + j;
      const float* wvp = Wpv + (size_t)c * (2 * CDIM) + h * HDM;
      const float* whp = Wph + (size_t)c * (2 * CDIM) + h * HDM;
      float ao = outAcc[j], as = stAcc[j];
#pragma unroll
      for (int d = 0; d < HDM; d++) {
        ao += a0r[d] * wvp[d];
        ao += a1r[d] * wvp[CDIM + d];
        as += a2r[d] * whp[d];
        as += a3r[d] * whp[CDIM + d];
      }
      outAcc[j] = ao; stAcc[j] = as;
    }
    __syncthreads();  // before next head's phase-1 LDS writes
  }

  // ---------- write out: out then state, concatenated flat
  float* orow = out + ((size_t)b * NSEQ + n2) * CDIM + qq * 24;
  float* srow = orow + (size_t)NB * NSEQ * CDIM;
#pragma unroll
  for (int j = 0; j < 24; j += 4) {
    *(float4*)(orow + j) = make_float4(outAcc[j], outAcc[j + 1], outAcc[j + 2], outAcc[j + 3]);
    *(float4*)(srow + j) = make_float4(stAcc[j], stAcc[j + 1], stAcc[j + 2], stAcc[j + 3]);
  }
}

extern "C" void kernel_launch(void* const* d_in, const int* in_sizes, int n_in,
                              void* d_out, int out_size, void* d_ws, size_t ws_size,
                              hipStream_t stream) {
  const float* input_x = (const float*)d_in[0];
  const float* state_x = (const float*)d_in[1];
  const float* Ws   = (const float*)d_in[2];
  const float* bs   = (const float*)d_in[3];
  const float* We   = (const float*)d_in[4];
  const float* be   = (const float*)d_in[5];
  const float* tcv  = (const float*)d_in[6];
  const float* tsv  = (const float*)d_in[7];
  const float* tch  = (const float*)d_in[8];
  const float* tsh  = (const float*)d_in[9];
  const float* Wpv  = (const float*)d_in[10];
  const float* bpv  = (const float*)d_in[11];
  const float* Wph  = (const float*)d_in[12];
  const float* bph  = (const float*)d_in[13];
  const int*   rel  = (const int*)d_in[14];

  float* bias = (float*)d_ws;  // 4*3*64*64 floats = 196608 B

  bias_pre_kernel<<<192, 256, 0, stream>>>(tcv, tsv, tch, tsh, rel, bias);
  rwa_kernel<<<NB, 256, 0, stream>>>(input_x, state_x, Ws, bs, We, be,
                                     Wpv, bpv, Wph, bph, bias, (float*)d_out);
}